// Round 7
// baseline (1524.522 us; speedup 1.0000x reference)
//
#include <hip/hip_runtime.h>

typedef unsigned short u16;
typedef unsigned int u32;

#define N_ATOMS 100000
#define N_BONDS 200000
#define N_EDGES 100000
#define HIDDEN 300
#define HP 320
#define ATOM_FDIM 133
#define BOND_FDIM 147
#define CATP 448
#define N_MOLS 2000

typedef __bf16 bf16x8 __attribute__((ext_vector_type(8)));
typedef float f32x4 __attribute__((ext_vector_type(4)));

__device__ __forceinline__ u16 f2bf(float f) {
    union { float f; u32 u; } x; x.f = f;
    u32 u = x.u;
    u32 r = u + 0x7fffu + ((u >> 16) & 1u);
    return (u16)(r >> 16);
}
__device__ __forceinline__ float bf2f(u16 h) {
    union { u32 u; float f; } x; x.u = ((u32)h) << 16;
    return x.f;
}

union U8 { uint4 v; u16 h[8]; };
union U4 { uint2 v; u16 h[4]; };

// ========== producer/consumer wave-specialized persistent GEMM ==========
// 512 threads = 8 waves. Waves 0-3: consumers — 32 rows x 320 cols MFMA tile
// (wave w owns cols w*80, operand-swapped mfma(B,A) -> lane holds 4 consecutive
// output cols). Waves 4-7: producers — gather/convert NEXT tile's A into the
// other LDS buffer. vmcnt is per-wave, so producer HBM gathers stay in flight
// across the consumers' entire compute phase. One barrier per tile.
//  ASRC 0: linear bf16 rows, stride LDA
//  ASRC 2: delta = srcA[i1[r]] - relu(srcB[i2[r]])   (both stride HP)
//  ASRC 3: cat   = [srcA[r] (HP, cols 300+ zero) | srcB[r] (160-wide pack)]
// EP 1: O1=bf16(acc); EP 2: O1=bf16(acc+inp_in); EP 3: O1=bf16(relu(acc+bias))
template<int ASRC, int EP, int KSTEPS, int LDA>
__global__ __launch_bounds__(512, 4) void k_gemm_pipe(
    const u16* __restrict__ srcA, const u16* __restrict__ srcB,
    const int* __restrict__ i1, const int* __restrict__ i2,
    int ntiles, const u16* __restrict__ Bt, int ldb,
    int Nout, const float* __restrict__ bias,
    u16* __restrict__ O1, const u16* __restrict__ inp_in)
{
    constexpr int CHPR = KSTEPS * 4;                 // 16B chunks per row
    constexpr int MASK = (CHPR % 8 == 0) ? 7 : 3;    // XOR swizzle domain
    constexpr int CPT = (CHPR + 7) / 8;              // chunks per producer thread
    __shared__ __align__(16) u16 As[2][32 * CHPR * 8];

    const int tid = threadIdx.x;
    const int wv = tid >> 6;
    const int tile0 = blockIdx.x;
    if (tile0 >= ntiles) return;

    if (wv >= 4) {
        // ---------------- producer path ----------------
        const int ptid = tid - 256;
        const int rr = ptid >> 3;      // row in tile (0..31)
        const int c0 = ptid & 7;       // chunk base

        uint4 sx[CPT], sy[(ASRC == 2) ? CPT : 1];

        auto stage = [&](int tile, int buf) {
            const int row = tile * 32 + rr;          // M % 32 == 0 always
            if constexpr (ASRC == 0) {
                const u16* px = srcA + (size_t)row * LDA;
#pragma unroll
                for (int j = 0; j < CPT; j++) {
                    int c = c0 + 8 * j;
                    if (CHPR % 8 == 0 || c < CHPR)
                        sx[j] = *(const uint4*)(px + c * 8);
                }
            } else if constexpr (ASRC == 2) {
                const u16* px = srcA + (size_t)i1[row] * HP;
                const u16* py = srcB + (size_t)i2[row] * HP;
#pragma unroll
                for (int j = 0; j < CPT; j++) {
                    int c = c0 + 8 * j;
                    sx[j] = *(const uint4*)(px + c * 8);
                    sy[j] = *(const uint4*)(py + c * 8);
                }
            } else {
                const u16* pa = srcA + (size_t)row * HP;
                const u16* pf = srcB + (size_t)row * 160;
#pragma unroll
                for (int j = 0; j < CPT; j++) {
                    int c = c0 + 8 * j;
                    sx[j] = (c < 38) ? *(const uint4*)(pa + c * 8)
                                     : *(const uint4*)(pf + (c - 38) * 8);
                }
            }
            // convert + write (compiler inserts the single vmcnt wait here)
#pragma unroll
            for (int j = 0; j < CPT; j++) {
                int c = c0 + 8 * j;
                if (CHPR % 8 != 0 && c >= CHPR) continue;
                U8 u;
                if constexpr (ASRC == 2) {
                    U8 x, y; x.v = sx[j]; y.v = sy[j];
#pragma unroll
                    for (int e = 0; e < 8; e++)
                        u.h[e] = f2bf(bf2f(x.h[e]) - fmaxf(bf2f(y.h[e]), 0.f));
                } else {
                    u.v = sx[j];
                }
                *(uint4*)&As[buf][(size_t)(rr * CHPR + (c ^ (rr & MASK))) * 8] = u.v;
            }
        };

        stage(tile0, 0);
        __syncthreads();
        int cur = 0;
        for (int tile = tile0;;) {
            int nxt = tile + gridDim.x;
            if (nxt >= ntiles) break;
            stage(nxt, cur ^ 1);
            __syncthreads();
            cur ^= 1; tile = nxt;
        }
    } else {
        // ---------------- consumer path ----------------
        const int lane = tid & 63;
        const int ncol0 = wv * 80;
        const int lrow = lane & 15;
        const int g = lane >> 4;
        const int lkb = g * 8;
        const int xr = lrow & MASK;

        const u16* pb[5];
#pragma unroll
        for (int n = 0; n < 5; n++)
            pb[n] = Bt + (size_t)(ncol0 + n * 16 + lrow) * ldb + lkb;

        auto compute = [&](int tile, int buf) {
            f32x4 acc[2][5] = {};
            bf16x8 bcur[5], bnxt[5];
#pragma unroll
            for (int n = 0; n < 5; n++) bcur[n] = *(const bf16x8*)(pb[n]);
#pragma unroll
            for (int ks = 0; ks < KSTEPS; ks++) {
                if (ks + 1 < KSTEPS) {
#pragma unroll
                    for (int n = 0; n < 5; n++) bnxt[n] = *(const bf16x8*)(pb[n] + (ks + 1) * 32);
                }
                const int sw = (ks * 4 + g) ^ xr;
                bf16x8 a0 = *(const bf16x8*)&As[buf][(size_t)(lrow * CHPR + sw) * 8];
                bf16x8 a1 = *(const bf16x8*)&As[buf][(size_t)((lrow + 16) * CHPR + sw) * 8];
#pragma unroll
                for (int n = 0; n < 5; n++) {
                    acc[0][n] = __builtin_amdgcn_mfma_f32_16x16x32_bf16(bcur[n], a0, acc[0][n], 0, 0, 0);
                    acc[1][n] = __builtin_amdgcn_mfma_f32_16x16x32_bf16(bcur[n], a1, acc[1][n], 0, 0, 0);
                }
#pragma unroll
                for (int n = 0; n < 5; n++) bcur[n] = bnxt[n];
            }
            const int row0 = tile * 32;
#pragma unroll
            for (int m = 0; m < 2; m++) {
                const int row = row0 + m * 16 + lrow;
#pragma unroll
                for (int n = 0; n < 5; n++) {
                    const int colb = ncol0 + n * 16 + g * 4;
                    U4 o;
                    if constexpr (EP == 1) {
#pragma unroll
                        for (int q = 0; q < 4; q++) o.h[q] = f2bf(acc[m][n][q]);
                    } else if constexpr (EP == 2) {
                        U4 ii; ii.v = *(const uint2*)&inp_in[(size_t)row * HP + colb];
#pragma unroll
                        for (int q = 0; q < 4; q++) o.h[q] = f2bf(acc[m][n][q] + bf2f(ii.h[q]));
                    } else {
#pragma unroll
                        for (int q = 0; q < 4; q++) {
                            float x = acc[m][n][q] + ((colb + q) < Nout ? bias[colb + q] : 0.f);
                            o.h[q] = f2bf(fmaxf(x, 0.f));
                        }
                    }
                    *(uint2*)&O1[(size_t)row * HP + colb] = o.v;
                }
            }
        };

        __syncthreads();
        int cur = 0;
        for (int tile = tile0;;) {
            int nxt = tile + gridDim.x;
            compute(tile, cur);
            if (nxt >= ntiles) break;
            __syncthreads();
            cur ^= 1; tile = nxt;
        }
    }
}

// =================== barrier-free direct-from-global MFMA GEMM ===================
// (node head ASRC0 and edge head ASRC4/WAVEM1)
template<int ASRC, int EP, int KSTEPS, int NFW, int WAVEM>
__global__ __launch_bounds__(256) void k_gemm(
    const float* __restrict__ fsrc, const u16* __restrict__ src16,
    const u16* __restrict__ src16b, const int* __restrict__ i1,
    const int* __restrict__ i2, int lda, int M,
    const u16* __restrict__ Bt, int ldb,
    int Nout, float* __restrict__ Cf, int ldc,
    const float* __restrict__ bias, u16* __restrict__ O1,
    const u16* __restrict__ inp_in)
{
    const int tid = threadIdx.x;
    const int lane = tid & 63;
    const int w = tid >> 6;
    const int lrow = lane & 15;
    const int lkb = (lane >> 4) * 8;

    int row0, ncol0;
    if constexpr (WAVEM) { row0 = blockIdx.x * 128 + w * 32; ncol0 = 0; }
    else                 { row0 = blockIdx.x * 32;           ncol0 = w * (NFW * 16); }

    const u16* pa[2] = {nullptr, nullptr};
    const u16* pa2[2] = {nullptr, nullptr};
#pragma unroll
    for (int m = 0; m < 2; m++) {
        int r = row0 + m * 16 + lrow; if (r >= M) r = M - 1;
        if constexpr (ASRC == 0) pa[m] = src16 + (size_t)r * lda + lkb;
        if constexpr (ASRC == 4) {
            int e = 2 * r;
            pa[m]  = src16 + (size_t)i1[e] * HP + lkb;
            pa2[m] = src16 + (size_t)i1[i2[e]] * HP + lkb;
        }
    }

    const u16* pb[NFW];
#pragma unroll
    for (int n = 0; n < NFW; n++)
        pb[n] = Bt + (size_t)(ncol0 + n * 16 + lrow) * ldb + lkb;

    auto loadAfrag = [&](int m, int k0) -> bf16x8 {
        U8 u;
        if constexpr (ASRC == 0) {
            u.v = *(const uint4*)(pa[m] + k0);
        } else {
            U8 x, y; x.v = *(const uint4*)(pa[m] + k0); y.v = *(const uint4*)(pa2[m] + k0);
#pragma unroll
            for (int e = 0; e < 8; e++)
                u.h[e] = f2bf(0.5f * (bf2f(x.h[e]) + bf2f(y.h[e])));
        }
        return *(bf16x8*)&u;
    };

    f32x4 acc[2][NFW] = {};

#pragma unroll
    for (int ks = 0; ks < KSTEPS; ks++) {
        const int k0 = ks * 32;
        bf16x8 a0 = loadAfrag(0, k0);
        bf16x8 a1 = loadAfrag(1, k0);
        bf16x8 bfr[NFW];
#pragma unroll
        for (int n = 0; n < NFW; n++) bfr[n] = *(const bf16x8*)(pb[n] + k0);
#pragma unroll
        for (int n = 0; n < NFW; n++) {
            acc[0][n] = __builtin_amdgcn_mfma_f32_16x16x32_bf16(a0, bfr[n], acc[0][n], 0, 0, 0);
            acc[1][n] = __builtin_amdgcn_mfma_f32_16x16x32_bf16(a1, bfr[n], acc[1][n], 0, 0, 0);
        }
    }

    const int orow = (lane >> 4) * 4;
    const int ocol = lane & 15;
#pragma unroll
    for (int m = 0; m < 2; m++) {
#pragma unroll
        for (int n = 0; n < NFW; n++) {
#pragma unroll
            for (int q = 0; q < 4; q++) {
                int grow = row0 + m * 16 + orow + q;
                int gcol = ncol0 + n * 16 + ocol;
                float v = acc[m][n][q];
                if constexpr (EP == 0) {
                    if (grow < M && gcol < Nout)
                        Cf[(size_t)grow * ldc + gcol] = v + bias[gcol];
                } else {
                    if (grow < M) O1[(size_t)grow * HP + gcol] = f2bf(v);
                }
            }
        }
    }
}

// ---------------- weight pack: Bt[n][k] = W[k][n], bf16, zero-padded ----------------
__global__ void k_pack_wt(const float* __restrict__ W, u16* __restrict__ Bt,
                          int K, int N, int Kp, int Np)
{
    int idx = blockIdx.x * 256 + threadIdx.x;
    if (idx >= Np * Kp) return;
    int n = idx / Kp, k = idx - n * Kp;
    Bt[idx] = (n < N && k < K) ? f2bf(W[(size_t)k * N + n]) : (u16)0;
}

// W_o pack with the [amsg(300) | pad4 | f_atoms(133) | pad] column reorder
__global__ void k_pack_wo(const float* __restrict__ W, u16* __restrict__ Bt)
{
    int idx = blockIdx.x * 256 + threadIdx.x;
    if (idx >= 320 * CATP) return;
    int n = idx / CATP, k = idx - n * CATP;
    float v = 0.f;
    if (n < HIDDEN) {
        if (k < HIDDEN) v = W[(size_t)(ATOM_FDIM + k) * HIDDEN + n];
        else if (k >= 304 && k < 304 + ATOM_FDIM) v = W[(size_t)(k - 304) * HIDDEN + n];
    }
    Bt[idx] = f2bf(v);
}

// ---------------- f_bonds fp32 [B][147] -> bf16 [B][160] ----------------
__global__ void k_pack_bonds(const float* __restrict__ fb, u16* __restrict__ out)
{
    int idx = blockIdx.x * 256 + threadIdx.x;
    if (idx >= N_BONDS * 160) return;
    int b = idx / 160, c = idx - b * 160;
    out[idx] = (c < BOND_FDIM) ? f2bf(fb[(size_t)b * BOND_FDIM + c]) : (u16)0;
}

// ---------------- f_atoms fp32 [A][133] -> bf16 [A][160] ----------------
__global__ void k_pack_fa(const float* __restrict__ fa, u16* __restrict__ out)
{
    int idx = blockIdx.x * 256 + threadIdx.x;
    if (idx >= N_ATOMS * 160) return;
    int a = idx / 160, c = idx - a * 160;
    out[idx] = (c < ATOM_FDIM) ? f2bf(fa[(size_t)a * ATOM_FDIM + c]) : (u16)0;
}

// ---------------- a_msg[a] = sum_j relu(h[a2b[a][j]]) ----------------
__global__ __launch_bounds__(256) void k_aggregate(const u16* __restrict__ h,
    const int* __restrict__ a2b, u16* __restrict__ amsg)
{
    int idx = blockIdx.x * 256 + threadIdx.x;
    if (idx >= N_ATOMS * 40) return;
    int a = idx / 40, c = (idx - a * 40) * 8;
    float s[8] = {};
#pragma unroll
    for (int j = 0; j < 6; j++) {
        int b = a2b[a * 6 + j];
        U8 u; u.v = *(const uint4*)&h[(size_t)b * HP + c];
#pragma unroll
        for (int i = 0; i < 8; i++) s[i] += fmaxf(bf2f(u.h[i]), 0.f);
    }
    U8 o;
#pragma unroll
    for (int i = 0; i < 8; i++) o.h[i] = f2bf(s[i]);
    *(uint4*)&amsg[(size_t)a * HP + c] = o.v;
}

// ---------------- per-molecule segment sum (graph_idx sorted) ----------------
__device__ __forceinline__ int lower_bound_i(const int* a, int n, int v) {
    int lo = 0, hi = n;
    while (lo < hi) { int mid = (lo + hi) >> 1; if (a[mid] < v) lo = mid + 1; else hi = mid; }
    return lo;
}
__global__ __launch_bounds__(320) void k_segsum(const u16* __restrict__ ah,
    const int* __restrict__ gidx, float* __restrict__ gemb)
{
    int g = blockIdx.x;
    int c = threadIdx.x;
    int s = lower_bound_i(gidx, N_ATOMS, g);
    int e = lower_bound_i(gidx, N_ATOMS, g + 1);
    float sum = 0.f;
    for (int a = s; a < e; a++) sum += bf2f(ah[(size_t)a * HP + c]);
    gemb[(size_t)g * HP + c] = sum;
}

// ---------------- graph head (fp32) ----------------
__global__ __launch_bounds__(320) void k_g1(const float* __restrict__ gemb,
    const float* __restrict__ W, const float* __restrict__ b, float* __restrict__ gh)
{
    int g = blockIdx.x, j = threadIdx.x;
    float acc = 0.f;
    if (j < HIDDEN) {
        acc = b[j];
        for (int k = 0; k < HIDDEN; k++)
            acc = fmaf(gemb[(size_t)g * HP + k], W[(size_t)k * HIDDEN + j], acc);
        acc = fmaxf(acc, 0.f);
    }
    gh[(size_t)g * HP + j] = (j < HIDDEN) ? acc : 0.f;
}
__global__ __launch_bounds__(64) void k_g2(const float* __restrict__ gh,
    const float* __restrict__ W, const float* __restrict__ b, float* __restrict__ out)
{
    int g = blockIdx.x, l = threadIdx.x;
    float acc = 0.f;
    for (int j = l; j < HIDDEN; j += 64) acc += gh[(size_t)g * HP + j] * W[j];
#pragma unroll
    for (int off = 32; off; off >>= 1) acc += __shfl_down(acc, off, 64);
    if (l == 0) out[g] = acc + b[0];
}

extern "C" void kernel_launch(void* const* d_in, const int* in_sizes, int n_in,
                              void* d_out, int out_size, void* d_ws, size_t ws_size,
                              hipStream_t stream)
{
    const float* f_atoms = (const float*)d_in[0];
    const float* f_bonds = (const float*)d_in[1];
    const int* a2b    = (const int*)d_in[2];
    const int* b2a    = (const int*)d_in[3];
    const int* b2revb = (const int*)d_in[4];
    const int* gidx   = (const int*)d_in[5];
    const float* W_i    = (const float*)d_in[6];
    const float* W_h    = (const float*)d_in[7];
    const float* W_o    = (const float*)d_in[8];
    const float* b_o    = (const float*)d_in[9];
    const float* W_node = (const float*)d_in[10];
    const float* b_node = (const float*)d_in[11];
    const float* W_edge = (const float*)d_in[12];
    const float* b_edge = (const float*)d_in[13];
    const float* W_g1   = (const float*)d_in[14];
    const float* b_g1   = (const float*)d_in[15];
    const float* W_g2   = (const float*)d_in[16];
    const float* b_g2   = (const float*)d_in[17];

    char* ws = (char*)d_ws;
    u16* inp  = (u16*)(ws + 0);            // 128 MB (h1 pre-relu input term)
    u16* hA   = (u16*)(ws + 128000000);    // 128 MB; reused as ah
    u16* hB   = (u16*)(ws + 256000000);    // 128 MB; fbpack -> h2 -> fapack
    u16* amsg = (u16*)(ws + 384000000);    // 64 MB
    u16* wt_i = (u16*)(ws + 448000000);    // 320x160
    u16* wt_h = (u16*)(ws + 448200000);    // 320x320
    u16* wt_o = (u16*)(ws + 448500000);    // 320x448
    u16* wt_n = (u16*)(ws + 448800000);    // 192x320
    u16* wt_e = (u16*)(ws + 449000000);    // 64x320
    float* gemb = (float*)(ws + 449300000); // 2000x320 f32
    float* gh   = (float*)(ws + 452000000); // 2000x320 f32

    float* out_node  = (float*)d_out;
    float* out_edge  = out_node + (size_t)N_ATOMS * ATOM_FDIM;
    float* out_graph = out_node + 14700000;

    dim3 blk(256);
    dim3 blk512(512);

    // pack weights (bf16, transposed, zero-padded)
    k_pack_wt<<<(320 * 160 + 255) / 256, blk, 0, stream>>>(W_i, wt_i, BOND_FDIM, HIDDEN, 160, 320);
    k_pack_wt<<<(320 * 320 + 255) / 256, blk, 0, stream>>>(W_h, wt_h, HIDDEN, HIDDEN, 320, 320);
    k_pack_wo<<<(320 * CATP + 255) / 256, blk, 0, stream>>>(W_o, wt_o);
    k_pack_wt<<<(192 * 320 + 255) / 256, blk, 0, stream>>>(W_node, wt_n, HIDDEN, ATOM_FDIM, 320, 192);
    k_pack_wt<<<(64 * 320 + 255) / 256, blk, 0, stream>>>(W_edge, wt_e, HIDDEN, 14, 320, 64);

    const int ntB = N_BONDS / 32;   // 6250
    const int ntA = N_ATOMS / 32;   // 3125
    const int GP = 512;             // persistent pipe grid
    const int gA32 = (N_ATOMS + 31) / 32;
    const int gE128 = (N_EDGES + 127) / 128;
    const int gAg = (N_ATOMS * 40 + 255) / 256;

    // pack f_bonds -> bf16[200k][160] into hB (dead until d=1 output)
    u16* fbpack = hB;
    k_pack_bonds<<<(N_BONDS * 160 + 255) / 256, blk, 0, stream>>>(f_bonds, fbpack);

    // inp = f_bonds @ W_i  (pre-relu stored)
    k_gemm_pipe<0, 1, 5, 160><<<GP, blk512, 0, stream>>>(
        fbpack, nullptr, nullptr, nullptr, ntB,
        wt_i, 160, 0, nullptr, inp, nullptr);

    // depth loop: h_{d+1} = inp + (amsg[b2a] - relu(h_d[b2revb])) @ W_h
    const u16* hcur = inp;
    u16* houts[2] = { hA, hB };
    for (int d = 0; d < 2; ++d) {
        k_aggregate<<<gAg, blk, 0, stream>>>(hcur, a2b, amsg);
        k_gemm_pipe<2, 2, 10, 0><<<GP, blk512, 0, stream>>>(
            amsg, hcur, b2a, b2revb, ntB,
            wt_h, 320, 0, nullptr, houts[d], inp);
        hcur = houts[d];
    }

    // final aggregate; pack f_atoms into hB (h2 dead after aggregate)
    k_aggregate<<<gAg, blk, 0, stream>>>(hcur, a2b, amsg);
    u16* fapack = hB;
    k_pack_fa<<<(N_ATOMS * 160 + 255) / 256, blk, 0, stream>>>(f_atoms, fapack);

    // atom_hiddens = relu([a_msg | f_atoms] @ W_o + b_o)  -> ah (bf16)
    u16* ah = hA;
    k_gemm_pipe<3, 3, 14, 0><<<GP, blk512, 0, stream>>>(
        amsg, fapack, nullptr, nullptr, ntA,
        wt_o, CATP, HIDDEN, b_o, ah, nullptr);

    // node head (linear A, direct; cols 0..191 computed, 0..132 stored)
    k_gemm<0, 0, 10, 3, 0><<<gA32, blk, 0, stream>>>(
        nullptr, ah, nullptr, nullptr, nullptr, HP, N_ATOMS,
        wt_n, 320, ATOM_FDIM, out_node, ATOM_FDIM, b_node, nullptr, nullptr);

    // edge head (fused h_avg gather; waves tile M, 1 col-frag)
    k_gemm<4, 0, 10, 1, 1><<<gE128, blk, 0, stream>>>(
        nullptr, ah, nullptr, b2a, b2revb, 0, N_EDGES,
        wt_e, 320, 14, out_edge, 14, b_edge, nullptr, nullptr);

    // graph head
    k_segsum<<<N_MOLS, 320, 0, stream>>>(ah, gidx, gemb);
    k_g1<<<N_MOLS, 320, 0, stream>>>(gemb, W_g1, b_g1, gh);
    k_g2<<<N_MOLS, 64, 0, stream>>>(gh, W_g2, b_g2, out_graph);
}

// Round 8
// 1260.817 us; speedup vs baseline: 1.2092x; 1.2092x over previous
//
#include <hip/hip_runtime.h>

typedef unsigned short u16;
typedef unsigned int u32;

#define N_ATOMS 100000
#define N_BONDS 200000
#define N_EDGES 100000
#define HIDDEN 300
#define HP 320
#define ATOM_FDIM 133
#define BOND_FDIM 147
#define CATP 448
#define N_MOLS 2000

typedef __bf16 bf16x8 __attribute__((ext_vector_type(8)));
typedef float f32x4 __attribute__((ext_vector_type(4)));

__device__ __forceinline__ u16 f2bf(float f) {
    union { float f; u32 u; } x; x.f = f;
    u32 u = x.u;
    u32 r = u + 0x7fffu + ((u >> 16) & 1u);
    return (u16)(r >> 16);
}
__device__ __forceinline__ float bf2f(u16 h) {
    union { u32 u; float f; } x; x.u = ((u32)h) << 16;
    return x.f;
}

union U8 { uint4 v; u16 h[8]; };
union U4 { uint2 v; u16 h[4]; };

// ========== producer/consumer wave-specialized persistent GEMM ==========
// 512 threads = 8 waves. Waves 0-3: consumers — 32 rows x 320 cols MFMA tile
// (wave w owns cols w*80, operand-swapped mfma(B,A) -> lane holds 4 consecutive
// output cols). Waves 4-7: producers — gather/convert NEXT tile's A into the
// other LDS buffer. vmcnt is per-wave, so producer HBM gathers stay in flight
// across the consumers' entire compute phase. One barrier per tile.
// launch_bounds(512,2): 256-VGPR cap — consumer needs ~100 live regs; the
// (512,4)/128-cap variant spilled acc+prefetch to scratch (R7: +500MB FETCH).
//  ASRC 0: linear bf16 rows, stride LDA
//  ASRC 2: delta = srcA[i1[r]] - relu(srcB[i2[r]])   (both stride HP)
//  ASRC 3: cat   = [srcA[r] (HP, cols 300+ zero) | srcB[r] (160-wide pack)]
// EP 1: O1=bf16(acc); EP 2: O1=bf16(acc+inp_in); EP 3: O1=bf16(relu(acc+bias))
template<int ASRC, int EP, int KSTEPS, int LDA>
__global__ __launch_bounds__(512, 2) void k_gemm_pipe(
    const u16* __restrict__ srcA, const u16* __restrict__ srcB,
    const int* __restrict__ i1, const int* __restrict__ i2,
    int ntiles, const u16* __restrict__ Bt, int ldb,
    int Nout, const float* __restrict__ bias,
    u16* __restrict__ O1, const u16* __restrict__ inp_in)
{
    constexpr int CHPR = KSTEPS * 4;                 // 16B chunks per row
    constexpr int MASK = (CHPR % 8 == 0) ? 7 : 3;    // XOR swizzle domain
    constexpr int CPT = (CHPR + 7) / 8;              // chunks per producer thread
    __shared__ __align__(16) u16 As[2][32 * CHPR * 8];

    const int tid = threadIdx.x;
    const int wv = tid >> 6;
    const int tile0 = blockIdx.x;
    if (tile0 >= ntiles) return;

    if (wv >= 4) {
        // ---------------- producer path ----------------
        const int ptid = tid - 256;
        const int rr = ptid >> 3;      // row in tile (0..31)
        const int c0 = ptid & 7;       // chunk base

        uint4 sx[CPT], sy[(ASRC == 2) ? CPT : 1];

        auto stage = [&](int tile, int buf) {
            const int row = tile * 32 + rr;          // M % 32 == 0 always
            if constexpr (ASRC == 0) {
                const u16* px = srcA + (size_t)row * LDA;
#pragma unroll
                for (int j = 0; j < CPT; j++) {
                    int c = c0 + 8 * j;
                    if (CHPR % 8 == 0 || c < CHPR)
                        sx[j] = *(const uint4*)(px + c * 8);
                }
            } else if constexpr (ASRC == 2) {
                const u16* px = srcA + (size_t)i1[row] * HP;
                const u16* py = srcB + (size_t)i2[row] * HP;
#pragma unroll
                for (int j = 0; j < CPT; j++) {
                    int c = c0 + 8 * j;
                    sx[j] = *(const uint4*)(px + c * 8);
                    sy[j] = *(const uint4*)(py + c * 8);
                }
            } else {
                const u16* pa = srcA + (size_t)row * HP;
                const u16* pf = srcB + (size_t)row * 160;
#pragma unroll
                for (int j = 0; j < CPT; j++) {
                    int c = c0 + 8 * j;
                    sx[j] = (c < 38) ? *(const uint4*)(pa + c * 8)
                                     : *(const uint4*)(pf + (c - 38) * 8);
                }
            }
            // convert + write (compiler inserts the single vmcnt wait here)
#pragma unroll
            for (int j = 0; j < CPT; j++) {
                int c = c0 + 8 * j;
                if (CHPR % 8 != 0 && c >= CHPR) continue;
                U8 u;
                if constexpr (ASRC == 2) {
                    U8 x, y; x.v = sx[j]; y.v = sy[j];
#pragma unroll
                    for (int e = 0; e < 8; e++)
                        u.h[e] = f2bf(bf2f(x.h[e]) - fmaxf(bf2f(y.h[e]), 0.f));
                } else {
                    u.v = sx[j];
                }
                *(uint4*)&As[buf][(size_t)(rr * CHPR + (c ^ (rr & MASK))) * 8] = u.v;
            }
        };

        stage(tile0, 0);
        __syncthreads();
        int cur = 0;
        for (int tile = tile0;;) {
            int nxt = tile + gridDim.x;
            if (nxt >= ntiles) break;
            stage(nxt, cur ^ 1);
            __syncthreads();
            cur ^= 1; tile = nxt;
        }
    } else {
        // ---------------- consumer path ----------------
        const int lane = tid & 63;
        const int ncol0 = wv * 80;
        const int lrow = lane & 15;
        const int g = lane >> 4;
        const int lkb = g * 8;
        const int xr = lrow & MASK;

        const u16* pb[5];
#pragma unroll
        for (int n = 0; n < 5; n++)
            pb[n] = Bt + (size_t)(ncol0 + n * 16 + lrow) * ldb + lkb;

        auto compute = [&](int tile, int buf) {
            f32x4 acc[2][5] = {};
            bf16x8 bcur[5], bnxt[5];
#pragma unroll
            for (int n = 0; n < 5; n++) bcur[n] = *(const bf16x8*)(pb[n]);
#pragma unroll
            for (int ks = 0; ks < KSTEPS; ks++) {
                if (ks + 1 < KSTEPS) {
#pragma unroll
                    for (int n = 0; n < 5; n++) bnxt[n] = *(const bf16x8*)(pb[n] + (ks + 1) * 32);
                }
                const int sw = (ks * 4 + g) ^ xr;
                bf16x8 a0 = *(const bf16x8*)&As[buf][(size_t)(lrow * CHPR + sw) * 8];
                bf16x8 a1 = *(const bf16x8*)&As[buf][(size_t)((lrow + 16) * CHPR + sw) * 8];
#pragma unroll
                for (int n = 0; n < 5; n++) {
                    acc[0][n] = __builtin_amdgcn_mfma_f32_16x16x32_bf16(bcur[n], a0, acc[0][n], 0, 0, 0);
                    acc[1][n] = __builtin_amdgcn_mfma_f32_16x16x32_bf16(bcur[n], a1, acc[1][n], 0, 0, 0);
                }
#pragma unroll
                for (int n = 0; n < 5; n++) bcur[n] = bnxt[n];
            }
            const int row0 = tile * 32;
#pragma unroll
            for (int m = 0; m < 2; m++) {
                const int row = row0 + m * 16 + lrow;
#pragma unroll
                for (int n = 0; n < 5; n++) {
                    const int colb = ncol0 + n * 16 + g * 4;
                    U4 o;
                    if constexpr (EP == 1) {
#pragma unroll
                        for (int q = 0; q < 4; q++) o.h[q] = f2bf(acc[m][n][q]);
                    } else if constexpr (EP == 2) {
                        U4 ii; ii.v = *(const uint2*)&inp_in[(size_t)row * HP + colb];
#pragma unroll
                        for (int q = 0; q < 4; q++) o.h[q] = f2bf(acc[m][n][q] + bf2f(ii.h[q]));
                    } else {
#pragma unroll
                        for (int q = 0; q < 4; q++) {
                            float x = acc[m][n][q] + ((colb + q) < Nout ? bias[colb + q] : 0.f);
                            o.h[q] = f2bf(fmaxf(x, 0.f));
                        }
                    }
                    *(uint2*)&O1[(size_t)row * HP + colb] = o.v;
                }
            }
        };

        __syncthreads();
        int cur = 0;
        for (int tile = tile0;;) {
            int nxt = tile + gridDim.x;
            compute(tile, cur);
            if (nxt >= ntiles) break;
            __syncthreads();
            cur ^= 1; tile = nxt;
        }
    }
}

// =================== barrier-free direct-from-global MFMA GEMM ===================
// (node head ASRC0 and edge head ASRC4/WAVEM1)
template<int ASRC, int EP, int KSTEPS, int NFW, int WAVEM>
__global__ __launch_bounds__(256) void k_gemm(
    const float* __restrict__ fsrc, const u16* __restrict__ src16,
    const u16* __restrict__ src16b, const int* __restrict__ i1,
    const int* __restrict__ i2, int lda, int M,
    const u16* __restrict__ Bt, int ldb,
    int Nout, float* __restrict__ Cf, int ldc,
    const float* __restrict__ bias, u16* __restrict__ O1,
    const u16* __restrict__ inp_in)
{
    const int tid = threadIdx.x;
    const int lane = tid & 63;
    const int w = tid >> 6;
    const int lrow = lane & 15;
    const int lkb = (lane >> 4) * 8;

    int row0, ncol0;
    if constexpr (WAVEM) { row0 = blockIdx.x * 128 + w * 32; ncol0 = 0; }
    else                 { row0 = blockIdx.x * 32;           ncol0 = w * (NFW * 16); }

    const u16* pa[2] = {nullptr, nullptr};
    const u16* pa2[2] = {nullptr, nullptr};
#pragma unroll
    for (int m = 0; m < 2; m++) {
        int r = row0 + m * 16 + lrow; if (r >= M) r = M - 1;
        if constexpr (ASRC == 0) pa[m] = src16 + (size_t)r * lda + lkb;
        if constexpr (ASRC == 4) {
            int e = 2 * r;
            pa[m]  = src16 + (size_t)i1[e] * HP + lkb;
            pa2[m] = src16 + (size_t)i1[i2[e]] * HP + lkb;
        }
    }

    const u16* pb[NFW];
#pragma unroll
    for (int n = 0; n < NFW; n++)
        pb[n] = Bt + (size_t)(ncol0 + n * 16 + lrow) * ldb + lkb;

    auto loadAfrag = [&](int m, int k0) -> bf16x8 {
        U8 u;
        if constexpr (ASRC == 0) {
            u.v = *(const uint4*)(pa[m] + k0);
        } else {
            U8 x, y; x.v = *(const uint4*)(pa[m] + k0); y.v = *(const uint4*)(pa2[m] + k0);
#pragma unroll
            for (int e = 0; e < 8; e++)
                u.h[e] = f2bf(0.5f * (bf2f(x.h[e]) + bf2f(y.h[e])));
        }
        return *(bf16x8*)&u;
    };

    f32x4 acc[2][NFW] = {};

#pragma unroll
    for (int ks = 0; ks < KSTEPS; ks++) {
        const int k0 = ks * 32;
        bf16x8 a0 = loadAfrag(0, k0);
        bf16x8 a1 = loadAfrag(1, k0);
        bf16x8 bfr[NFW];
#pragma unroll
        for (int n = 0; n < NFW; n++) bfr[n] = *(const bf16x8*)(pb[n] + k0);
#pragma unroll
        for (int n = 0; n < NFW; n++) {
            acc[0][n] = __builtin_amdgcn_mfma_f32_16x16x32_bf16(a0, bfr[n], acc[0][n], 0, 0, 0);
            acc[1][n] = __builtin_amdgcn_mfma_f32_16x16x32_bf16(a1, bfr[n], acc[1][n], 0, 0, 0);
        }
    }

    const int orow = (lane >> 4) * 4;
    const int ocol = lane & 15;
#pragma unroll
    for (int m = 0; m < 2; m++) {
#pragma unroll
        for (int n = 0; n < NFW; n++) {
#pragma unroll
            for (int q = 0; q < 4; q++) {
                int grow = row0 + m * 16 + orow + q;
                int gcol = ncol0 + n * 16 + ocol;
                float v = acc[m][n][q];
                if constexpr (EP == 0) {
                    if (grow < M && gcol < Nout)
                        Cf[(size_t)grow * ldc + gcol] = v + bias[gcol];
                } else {
                    if (grow < M) O1[(size_t)grow * HP + gcol] = f2bf(v);
                }
            }
        }
    }
}

// ---------------- weight pack: Bt[n][k] = W[k][n], bf16, zero-padded ----------------
__global__ void k_pack_wt(const float* __restrict__ W, u16* __restrict__ Bt,
                          int K, int N, int Kp, int Np)
{
    int idx = blockIdx.x * 256 + threadIdx.x;
    if (idx >= Np * Kp) return;
    int n = idx / Kp, k = idx - n * Kp;
    Bt[idx] = (n < N && k < K) ? f2bf(W[(size_t)k * N + n]) : (u16)0;
}

// W_o pack with the [amsg(300) | pad4 | f_atoms(133) | pad] column reorder
__global__ void k_pack_wo(const float* __restrict__ W, u16* __restrict__ Bt)
{
    int idx = blockIdx.x * 256 + threadIdx.x;
    if (idx >= 320 * CATP) return;
    int n = idx / CATP, k = idx - n * CATP;
    float v = 0.f;
    if (n < HIDDEN) {
        if (k < HIDDEN) v = W[(size_t)(ATOM_FDIM + k) * HIDDEN + n];
        else if (k >= 304 && k < 304 + ATOM_FDIM) v = W[(size_t)(k - 304) * HIDDEN + n];
    }
    Bt[idx] = f2bf(v);
}

// ---------------- f_bonds fp32 [B][147] -> bf16 [B][160] ----------------
__global__ void k_pack_bonds(const float* __restrict__ fb, u16* __restrict__ out)
{
    int idx = blockIdx.x * 256 + threadIdx.x;
    if (idx >= N_BONDS * 160) return;
    int b = idx / 160, c = idx - b * 160;
    out[idx] = (c < BOND_FDIM) ? f2bf(fb[(size_t)b * BOND_FDIM + c]) : (u16)0;
}

// ---------------- f_atoms fp32 [A][133] -> bf16 [A][160] ----------------
__global__ void k_pack_fa(const float* __restrict__ fa, u16* __restrict__ out)
{
    int idx = blockIdx.x * 256 + threadIdx.x;
    if (idx >= N_ATOMS * 160) return;
    int a = idx / 160, c = idx - a * 160;
    out[idx] = (c < ATOM_FDIM) ? f2bf(fa[(size_t)a * ATOM_FDIM + c]) : (u16)0;
}

// ---------------- a_msg[a] = sum_j relu(h[a2b[a][j]]) ----------------
__global__ __launch_bounds__(256) void k_aggregate(const u16* __restrict__ h,
    const int* __restrict__ a2b, u16* __restrict__ amsg)
{
    int idx = blockIdx.x * 256 + threadIdx.x;
    if (idx >= N_ATOMS * 40) return;
    int a = idx / 40, c = (idx - a * 40) * 8;
    float s[8] = {};
#pragma unroll
    for (int j = 0; j < 6; j++) {
        int b = a2b[a * 6 + j];
        U8 u; u.v = *(const uint4*)&h[(size_t)b * HP + c];
#pragma unroll
        for (int i = 0; i < 8; i++) s[i] += fmaxf(bf2f(u.h[i]), 0.f);
    }
    U8 o;
#pragma unroll
    for (int i = 0; i < 8; i++) o.h[i] = f2bf(s[i]);
    *(uint4*)&amsg[(size_t)a * HP + c] = o.v;
}

// ---------------- per-molecule segment sum (graph_idx sorted) ----------------
__device__ __forceinline__ int lower_bound_i(const int* a, int n, int v) {
    int lo = 0, hi = n;
    while (lo < hi) { int mid = (lo + hi) >> 1; if (a[mid] < v) lo = mid + 1; else hi = mid; }
    return lo;
}
__global__ __launch_bounds__(320) void k_segsum(const u16* __restrict__ ah,
    const int* __restrict__ gidx, float* __restrict__ gemb)
{
    int g = blockIdx.x;
    int c = threadIdx.x;
    int s = lower_bound_i(gidx, N_ATOMS, g);
    int e = lower_bound_i(gidx, N_ATOMS, g + 1);
    float sum = 0.f;
    for (int a = s; a < e; a++) sum += bf2f(ah[(size_t)a * HP + c]);
    gemb[(size_t)g * HP + c] = sum;
}

// ---------------- graph head (fp32) ----------------
__global__ __launch_bounds__(320) void k_g1(const float* __restrict__ gemb,
    const float* __restrict__ W, const float* __restrict__ b, float* __restrict__ gh)
{
    int g = blockIdx.x, j = threadIdx.x;
    float acc = 0.f;
    if (j < HIDDEN) {
        acc = b[j];
        for (int k = 0; k < HIDDEN; k++)
            acc = fmaf(gemb[(size_t)g * HP + k], W[(size_t)k * HIDDEN + j], acc);
        acc = fmaxf(acc, 0.f);
    }
    gh[(size_t)g * HP + j] = (j < HIDDEN) ? acc : 0.f;
}
__global__ __launch_bounds__(64) void k_g2(const float* __restrict__ gh,
    const float* __restrict__ W, const float* __restrict__ b, float* __restrict__ out)
{
    int g = blockIdx.x, l = threadIdx.x;
    float acc = 0.f;
    for (int j = l; j < HIDDEN; j += 64) acc += gh[(size_t)g * HP + j] * W[j];
#pragma unroll
    for (int off = 32; off; off >>= 1) acc += __shfl_down(acc, off, 64);
    if (l == 0) out[g] = acc + b[0];
}

extern "C" void kernel_launch(void* const* d_in, const int* in_sizes, int n_in,
                              void* d_out, int out_size, void* d_ws, size_t ws_size,
                              hipStream_t stream)
{
    const float* f_atoms = (const float*)d_in[0];
    const float* f_bonds = (const float*)d_in[1];
    const int* a2b    = (const int*)d_in[2];
    const int* b2a    = (const int*)d_in[3];
    const int* b2revb = (const int*)d_in[4];
    const int* gidx   = (const int*)d_in[5];
    const float* W_i    = (const float*)d_in[6];
    const float* W_h    = (const float*)d_in[7];
    const float* W_o    = (const float*)d_in[8];
    const float* b_o    = (const float*)d_in[9];
    const float* W_node = (const float*)d_in[10];
    const float* b_node = (const float*)d_in[11];
    const float* W_edge = (const float*)d_in[12];
    const float* b_edge = (const float*)d_in[13];
    const float* W_g1   = (const float*)d_in[14];
    const float* b_g1   = (const float*)d_in[15];
    const float* W_g2   = (const float*)d_in[16];
    const float* b_g2   = (const float*)d_in[17];

    char* ws = (char*)d_ws;
    u16* inp  = (u16*)(ws + 0);            // 128 MB (h1 pre-relu input term)
    u16* hA   = (u16*)(ws + 128000000);    // 128 MB; reused as ah
    u16* hB   = (u16*)(ws + 256000000);    // 128 MB; fbpack -> h2 -> fapack
    u16* amsg = (u16*)(ws + 384000000);    // 64 MB
    u16* wt_i = (u16*)(ws + 448000000);    // 320x160
    u16* wt_h = (u16*)(ws + 448200000);    // 320x320
    u16* wt_o = (u16*)(ws + 448500000);    // 320x448
    u16* wt_n = (u16*)(ws + 448800000);    // 192x320
    u16* wt_e = (u16*)(ws + 449000000);    // 64x320
    float* gemb = (float*)(ws + 449300000); // 2000x320 f32
    float* gh   = (float*)(ws + 452000000); // 2000x320 f32

    float* out_node  = (float*)d_out;
    float* out_edge  = out_node + (size_t)N_ATOMS * ATOM_FDIM;
    float* out_graph = out_node + 14700000;

    dim3 blk(256);
    dim3 blk512(512);

    // pack weights (bf16, transposed, zero-padded)
    k_pack_wt<<<(320 * 160 + 255) / 256, blk, 0, stream>>>(W_i, wt_i, BOND_FDIM, HIDDEN, 160, 320);
    k_pack_wt<<<(320 * 320 + 255) / 256, blk, 0, stream>>>(W_h, wt_h, HIDDEN, HIDDEN, 320, 320);
    k_pack_wo<<<(320 * CATP + 255) / 256, blk, 0, stream>>>(W_o, wt_o);
    k_pack_wt<<<(192 * 320 + 255) / 256, blk, 0, stream>>>(W_node, wt_n, HIDDEN, ATOM_FDIM, 320, 192);
    k_pack_wt<<<(64 * 320 + 255) / 256, blk, 0, stream>>>(W_edge, wt_e, HIDDEN, 14, 320, 64);

    const int ntB = N_BONDS / 32;   // 6250
    const int ntA = N_ATOMS / 32;   // 3125
    const int GP = 512;             // persistent pipe grid
    const int gA32 = (N_ATOMS + 31) / 32;
    const int gE128 = (N_EDGES + 127) / 128;
    const int gAg = (N_ATOMS * 40 + 255) / 256;

    // pack f_bonds -> bf16[200k][160] into hB (dead until d=1 output)
    u16* fbpack = hB;
    k_pack_bonds<<<(N_BONDS * 160 + 255) / 256, blk, 0, stream>>>(f_bonds, fbpack);

    // inp = f_bonds @ W_i  (pre-relu stored)
    k_gemm_pipe<0, 1, 5, 160><<<GP, blk512, 0, stream>>>(
        fbpack, nullptr, nullptr, nullptr, ntB,
        wt_i, 160, 0, nullptr, inp, nullptr);

    // depth loop: h_{d+1} = inp + (amsg[b2a] - relu(h_d[b2revb])) @ W_h
    const u16* hcur = inp;
    u16* houts[2] = { hA, hB };
    for (int d = 0; d < 2; ++d) {
        k_aggregate<<<gAg, blk, 0, stream>>>(hcur, a2b, amsg);
        k_gemm_pipe<2, 2, 10, 0><<<GP, blk512, 0, stream>>>(
            amsg, hcur, b2a, b2revb, ntB,
            wt_h, 320, 0, nullptr, houts[d], inp);
        hcur = houts[d];
    }

    // final aggregate; pack f_atoms into hB (h2 dead after aggregate)
    k_aggregate<<<gAg, blk, 0, stream>>>(hcur, a2b, amsg);
    u16* fapack = hB;
    k_pack_fa<<<(N_ATOMS * 160 + 255) / 256, blk, 0, stream>>>(f_atoms, fapack);

    // atom_hiddens = relu([a_msg | f_atoms] @ W_o + b_o)  -> ah (bf16)
    u16* ah = hA;
    k_gemm_pipe<3, 3, 14, 0><<<GP, blk512, 0, stream>>>(
        amsg, fapack, nullptr, nullptr, ntA,
        wt_o, CATP, HIDDEN, b_o, ah, nullptr);

    // node head (linear A, direct; cols 0..191 computed, 0..132 stored)
    k_gemm<0, 0, 10, 3, 0><<<gA32, blk, 0, stream>>>(
        nullptr, ah, nullptr, nullptr, nullptr, HP, N_ATOMS,
        wt_n, 320, ATOM_FDIM, out_node, ATOM_FDIM, b_node, nullptr, nullptr);

    // edge head (fused h_avg gather; waves tile M, 1 col-frag)
    k_gemm<4, 0, 10, 1, 1><<<gE128, blk, 0, stream>>>(
        nullptr, ah, nullptr, b2a, b2revb, 0, N_EDGES,
        wt_e, 320, 14, out_edge, 14, b_edge, nullptr, nullptr);

    // graph head
    k_segsum<<<N_MOLS, 320, 0, stream>>>(ah, gidx, gemb);
    k_g1<<<N_MOLS, 320, 0, stream>>>(gemb, W_g1, b_g1, gh);
    k_g2<<<N_MOLS, 64, 0, stream>>>(gh, W_g2, b_g2, out_graph);
}